// Round 2
// baseline (232.796 us; speedup 1.0000x reference)
//
#include <hip/hip_runtime.h>
#include <hip/hip_bf16.h>
#include <math.h>

#define B_ 2
#define D_ 256
#define N_ 8192
#define CI_ 128
#define M_ 4096
#define BN_EPS_ 1e-5f
#define LOG2E_ 1.4426950408889634f

// ---- workspace layout (float offsets) ----
#define OFF_WALL 0                          // bf16 wall[384][256] + wall2[256][128]
#define OFF_THT  65536                      // theta bf16 [B][N][CI]  (pre-scaled by log2 e)
#define OFF_PHT  (OFF_THT + 1048576)        // phi   bf16 [B][M][CI]
#define OFF_GT   (OFF_PHT + 524288)         // g     bf16 [B][CI][M]
#define OFF_YP   (OFF_GT  + 524288)         // y partial bf16 [4][B][CI][N]
#define OFF_ML   (OFF_YP  + 4194304)        // m/l fp32 [4][B][2][N]  (m in log2 domain)
#define OFF_MEAN (OFF_ML + 131072)
#define OFF_RSTD (OFF_MEAN + 256)

typedef __attribute__((ext_vector_type(8))) short bfrag;    // 8 bf16 = 4 VGPRs
typedef __attribute__((ext_vector_type(4))) float f4v;      // 16x16 accumulator
typedef __attribute__((ext_vector_type(16))) float f16v;    // 32x32 accumulator
typedef __attribute__((ext_vector_type(4))) short s4v;      // 4 bf16
typedef __attribute__((ext_vector_type(4))) unsigned u4v;   // 4 dwords (for reg-only pf build)

__device__ inline unsigned short bf16rne(float x) {
    unsigned u = __float_as_uint(x);
    u += 0x7fff + ((u >> 16) & 1);
    return (unsigned short)(u >> 16);
}

// 2^x via v_exp_f32 directly (no ocml denorm path, no log2e mul)
__device__ inline float exp2fast(float x) {
    float r;
    asm("v_exp_f32 %0, %1" : "=v"(r) : "v"(x));
    return r;
}

// ---------------- pack weights to bf16: wall[384][256] (g|theta|phi), wall2[256][128] (W) ----
// theta weights are pre-scaled by log2(e) so attention softmax runs in exp2 domain.
__global__ __launch_bounds__(256) void wconv_kernel(
    const float* __restrict__ gw, const float* __restrict__ tw, const float* __restrict__ pw,
    const float* __restrict__ Ww, short* __restrict__ wall)
{
    int idx = blockIdx.x * 256 + threadIdx.x;      // 0 .. 131071
    int which = idx >> 15;
    int rem = idx & 32767;
    const float* src = (which == 0) ? gw : (which == 1) ? tw : (which == 2) ? pw : Ww;
    float v = src[rem];
    if (which == 1) v *= LOG2E_;
    wall[idx] = (short)bf16rne(v);
}

// ---------------- MFMA projections ----------------
// Out[cc][n] = sum_d Wall[cc][d] * f[b][d][n], cc in [0,384): g | theta | phi.
// block 256 = 4 waves; wave owns 96 cc (6 frags) x 32 n (2 frags). grid (N/32, B).
__global__ __launch_bounds__(256, 2) void proj_kernel(
    const float* __restrict__ f, const short* __restrict__ wall,
    const float* __restrict__ tb, const float* __restrict__ gb, const float* __restrict__ pb,
    short* __restrict__ th_t, short* __restrict__ g_t, short* __restrict__ ph_t)
{
    __shared__ short sF[32 * 72];   // f chunk transposed [n][k], stride 72 shorts

    const int tid = threadIdx.x;
    const int wave = tid >> 6, lane = tid & 63;
    const int lq = lane & 15, quad = lane >> 4;
    const int b = blockIdx.y;
    const int n0 = blockIdx.x * 32;

    const float* fb = f + (size_t)b * D_ * N_;

    f4v acc[6][2];
#pragma unroll
    for (int ct = 0; ct < 6; ct++)
#pragma unroll
        for (int nf = 0; nf < 2; nf++) acc[ct][nf] = (f4v){0.f, 0.f, 0.f, 0.f};

    const int sn = tid & 31;     // staging: n within tile
    const int sgrp = tid >> 5;   // staging: d' group of 8

    for (int kc = 0; kc < D_; kc += 64) {
        __syncthreads();
#pragma unroll
        for (int jj = 0; jj < 4; jj++) {
            int dd = kc + sgrp * 8 + 2 * jj;
            float v0 = fb[(size_t)dd * N_ + n0 + sn];
            float v1 = fb[(size_t)(dd + 1) * N_ + n0 + sn];
            unsigned pk = (unsigned)bf16rne(v0) | ((unsigned)bf16rne(v1) << 16);
            *(unsigned*)&sF[sn * 72 + sgrp * 8 + 2 * jj] = pk;
        }
        __syncthreads();

        bfrag afr[6][2], bfr[2][2];
#pragma unroll
        for (int ks = 0; ks < 2; ks++) {
#pragma unroll
            for (int nf = 0; nf < 2; nf++)
                bfr[nf][ks] = *(const bfrag*)&sF[(nf * 16 + lq) * 72 + ks * 32 + quad * 8];
#pragma unroll
            for (int ct = 0; ct < 6; ct++)
                afr[ct][ks] = *(const bfrag*)&wall[(wave * 96 + ct * 16 + lq) * 256 + kc + ks * 32 + quad * 8];
        }
#pragma unroll
        for (int ks = 0; ks < 2; ks++)
#pragma unroll
            for (int ct = 0; ct < 6; ct++) {
                acc[ct][0] = __builtin_amdgcn_mfma_f32_16x16x32_bf16(afr[ct][ks], bfr[0][ks], acc[ct][0], 0, 0, 0);
                acc[ct][1] = __builtin_amdgcn_mfma_f32_16x16x32_bf16(afr[ct][ks], bfr[1][ks], acc[ct][1], 0, 0, 0);
            }
    }

#pragma unroll
    for (int ct = 0; ct < 6; ct++) {
        const int cf = wave * 6 + ct;
#pragma unroll
        for (int nf = 0; nf < 2; nf++) {
            f4v v = acc[ct][nf];
            const int n = n0 + nf * 16 + lq;
            if (cf < 8) {                 // g -> pooled, transposed [c][m]
                const int cb = cf * 16 + quad * 4;
                float pl[4];
#pragma unroll
                for (int r = 0; r < 4; r++) {
                    float o = __shfl_xor(v[r], 1);
                    pl[r] = fmaxf(v[r], o) + gb[cb + r];
                }
                if (!(lq & 1)) {
                    const int m = n >> 1;
#pragma unroll
                    for (int r = 0; r < 4; r++)
                        g_t[((size_t)b * CI_ + cb + r) * M_ + m] = (short)bf16rne(pl[r]);
                }
            } else if (cf < 16) {         // theta [n][c], log2e-scaled (weights already scaled)
                const int cb = (cf - 8) * 16 + quad * 4;
                s4v o;
#pragma unroll
                for (int r = 0; r < 4; r++) o[r] = (short)bf16rne(v[r] + tb[cb + r] * LOG2E_);
                *(s4v*)&th_t[((size_t)b * N_ + n) * CI_ + cb] = o;
            } else {                      // phi -> pooled [m][c]
                const int cb = (cf - 16) * 16 + quad * 4;
                float pl[4];
#pragma unroll
                for (int r = 0; r < 4; r++) {
                    float o = __shfl_xor(v[r], 1);
                    pl[r] = fmaxf(v[r], o) + pb[cb + r];
                }
                if (!(lq & 1)) {
                    const int m = n >> 1;
                    s4v o;
#pragma unroll
                    for (int r = 0; r < 4; r++) o[r] = (short)bf16rne(pl[r]);
                    *(s4v*)&ph_t[((size_t)b * M_ + m) * CI_ + cb] = o;
                }
            }
        }
    }
}

// ---------------- MFMA flash attention, 32x32 tiles, key-split 4 ----------------
// block 256 = 4 waves; wave owns 32 q. Q-tile 128, KC=64 keys/chunk, 16 chunks.
// R1 fixes vs R0 (155 MB phantom WRITE_SIZE = scratch traffic):
//  (a) pf[] built via ext_vector + bit_cast (the union was an address-taken
//      aggregate -> scratch: 4x16B x 16 chunks x 131072 thr = the 134 MB excess);
//  (b) WRITE_CHUNK moved to right after QK (pinned by sched_barrier(0)) so the
//      32 prefetch VGPRs die before the softmax/PV pressure peak -> no spill;
//  (c) XCD-pinned remap: 8 (b,split) pairs -> 8 XCDs; phi/g slice (512 KB)
//      stays L2-resident per XCD, staging loads become L2-hits.
__global__ __launch_bounds__(256, 2) void attn_kernel(
    const short* __restrict__ th_p, const short* __restrict__ ph_p,
    const short* __restrict__ g_p, short* __restrict__ yp, float* __restrict__ ml)
{
    __shared__ short sPh[2][64 * 128];  // phi [key][ci], linear 256B rows, XOR-16 swizzle
    __shared__ short sG [2][128 * 72];  // g^T [c][key],  144 B rows (9x16B, odd)

    const int tid = threadIdx.x;
    const int wave = tid >> 6, lane = tid & 63;
    const int l = lane & 31, h = lane >> 5;

    // XCD-pinned decomposition: consecutive block ids round-robin across the 8
    // XCDs, and we have exactly 8 (b,split) pairs -> pin pair = bid&7.
    const int bid = blockIdx.x;
    const int b = bid & 1;
    const int split = (bid >> 1) & 3;
    const int q0 = (bid >> 3) * 128;
    const int qg = q0 + wave * 32 + l;

    // theta B-fragments in registers: B[k = 16s + 8h + j][n = q]
    const short* thr = th_p + ((size_t)b * N_ + qg) * CI_;
    bfrag tf[8];
#pragma unroll
    for (int s = 0; s < 8; s++)
        tf[s] = *(const bfrag*)&thr[s * 16 + h * 8];

    f16v yacc[4];
#pragma unroll
    for (int ct = 0; ct < 4; ct++)
#pragma unroll
        for (int r = 0; r < 16; r++) yacc[ct][r] = 0.f;
    float mI = -INFINITY, lI = 0.f;

    const short* phg = ph_p + (size_t)b * M_ * CI_;
    const short* gg  = g_p + (size_t)b * CI_ * M_;

    const int k0 = split * 1024;
    const int xm = l & 15;               // read-side swizzle mask for sPh

    // per-thread staging coords
    const int pr = tid >> 4, pc = tid & 15;   // phi: 16 rows x 16 slots per pass
    const int gr = tid >> 3, gu = tid & 7;    // g:   32 rows x 8 slots per pass

    float4 rph[4], rg[4];
#define LOAD_CHUNK(KC)                                                                      \
    do {                                                                                    \
        _Pragma("unroll")                                                                   \
        for (int p = 0; p < 4; p++)                                                         \
            rph[p] = *(const float4*)&phg[(size_t)((KC) + p * 16 + pr) * 128 + pc * 8];     \
        _Pragma("unroll")                                                                   \
        for (int p = 0; p < 4; p++)                                                         \
            rg[p] = *(const float4*)&gg[(size_t)(p * 32 + gr) * M_ + (KC) + gu * 8];        \
    } while (0)
    // write side: sPh slot = pc ^ (row & 15); row = p*16 + pr so row&15 == pr
#define WRITE_CHUNK(BUF)                                                                    \
    do {                                                                                    \
        _Pragma("unroll")                                                                   \
        for (int p = 0; p < 4; p++)                                                         \
            *(float4*)&sPh[BUF][(p * 16 + pr) * 128 + (pc ^ pr) * 8] = rph[p];              \
        _Pragma("unroll")                                                                   \
        for (int p = 0; p < 4; p++)                                                         \
            *(float4*)&sG[BUF][(p * 32 + gr) * 72 + gu * 8] = rg[p];                        \
    } while (0)

    LOAD_CHUNK(k0);
    WRITE_CHUNK(0);

    int cur = 0;
    for (int kc = k0; kc < k0 + 1024; kc += 64) {
        __syncthreads();                 // buf[cur] staged; buf[cur^1] free
        const bool nxt = (kc + 64 < k0 + 1024);
        if (nxt) LOAD_CHUNK(kc + 64);    // overlap HBM/L2 latency with QK below

        // S^T = phi . theta : 2 key-tiles of 32; lane holds col q = l, 16 key-rows/tile
        f16v sv[2];
        __builtin_amdgcn_s_setprio(1);
#pragma unroll
        for (int kt = 0; kt < 2; kt++) {
            f16v a;
#pragma unroll
            for (int r = 0; r < 16; r++) a[r] = 0.f;
#pragma unroll
            for (int s = 0; s < 8; s++) {
                bfrag pa = *(const bfrag*)&sPh[cur][(kt * 32 + l) * 128 + (((s << 1) | h) ^ xm) * 8];
                a = __builtin_amdgcn_mfma_f32_32x32x16_bf16(pa, tf[s], a, 0, 0, 0);
            }
            sv[kt] = a;
        }
        __builtin_amdgcn_s_setprio(0);

        // stage next chunk into the free buffer NOW: frees the 32 prefetch VGPRs
        // before the softmax/PV register-pressure peak (anti-spill). Legal: buf^1
        // was last read before the barrier above.
        if (nxt) {
            WRITE_CHUNK(cur ^ 1);
            __builtin_amdgcn_sched_barrier(0);   // pin: don't sink these ds_writes
        }

        // online softmax for q = l, exp2 domain (keys split across h halves: one shfl)
        float mx = fmaxf(sv[0][0], sv[1][0]);
#pragma unroll
        for (int r = 1; r < 16; r++) mx = fmaxf(mx, fmaxf(sv[0][r], sv[1][r]));
        mx = fmaxf(mx, __shfl_xor(mx, 32));

        // defer-max: only rescale when the running max grew by > 8 (p bounded by 2^8)
        if (__any(mx > mI + 8.f)) {
            float mnew = fmaxf(mI, mx);
            float al = exp2fast(mI - mnew);
            lI *= al;
#pragma unroll
            for (int ct = 0; ct < 4; ct++)
#pragma unroll
                for (int r = 0; r < 16; r++) yacc[ct][r] *= al;
            mI = mnew;
        }

        float ps = 0.f;
        // pack exp2(S) pairs: pw[kt*8 + b2*2 + p] holds keys kt*32 + 8*b2 + 4h + 2p + {0,1}
        unsigned pw[16];
#pragma unroll
        for (int kt = 0; kt < 2; kt++)
#pragma unroll
            for (int i = 0; i < 8; i++) {
                const int r = 2 * i;
                float p0 = exp2fast(sv[kt][r] - mI);
                float p1 = exp2fast(sv[kt][r + 1] - mI);
                ps += p0 + p1;
                unsigned pk;
                asm("v_cvt_pk_bf16_f32 %0, %1, %2" : "=v"(pk) : "v"(p0), "v"(p1));
                pw[kt * 8 + (i >> 1) * 2 + (i & 1)] = pk;
            }
        ps += __shfl_xor(ps, 32);
        lI += ps;

        // P -> B-operand frags: pf[s][j] = P[key = 16s + 8h + j][q = l].
        // value with key k: held at half bit2(k), needed at half bit3(k) -> one shfl_xor(32).
        // All pw[] indices are compile-time constants; h only selects VALUES (cndmask).
        // Register-only build: ext_vector element writes + bit_cast (NO union/address).
        bfrag pf[4];
#pragma unroll
        for (int s = 0; s < 4; s++) {
            const int kt = s >> 1;
            const int iA = kt * 8 + ((2 * s) & 3) * 2;       // block used when h==0 as "own"
            const int iB = kt * 8 + ((2 * s + 1) & 3) * 2;   // block used when h==1 as "own"
            unsigned A0 = pw[iA], A1 = pw[iA + 1];
            unsigned B0 = pw[iB], B1 = pw[iB + 1];
            unsigned O0 = h ? B0 : A0;
            unsigned O1 = h ? B1 : A1;
            unsigned Xs0 = h ? A0 : B0;
            unsigned Xs1 = h ? A1 : B1;
            unsigned X0 = (unsigned)__shfl_xor((int)Xs0, 32);
            unsigned X1 = (unsigned)__shfl_xor((int)Xs1, 32);
            u4v t;
            t.x = h ? X0 : O0;
            t.y = h ? X1 : O1;
            t.z = h ? O0 : X0;
            t.w = h ? O1 : X1;
            pf[s] = __builtin_bit_cast(bfrag, t);
        }

        // PV: y^T += g^T . P
        __builtin_amdgcn_s_setprio(1);
#pragma unroll
        for (int ct = 0; ct < 4; ct++)
#pragma unroll
            for (int s = 0; s < 4; s++) {
                bfrag ga = *(const bfrag*)&sG[cur][(ct * 32 + l) * 72 + s * 16 + h * 8];
                yacc[ct] = __builtin_amdgcn_mfma_f32_32x32x16_bf16(ga, pf[s], yacc[ct], 0, 0, 0);
            }
        __builtin_amdgcn_s_setprio(0);

        cur ^= 1;
    }
#undef LOAD_CHUNK
#undef WRITE_CHUNK

    // epilogue: bf16 unnormalized partials + (m,l)  (m in log2 domain)
    short* yb = yp + (((size_t)split * B_ + b) * CI_) * N_;
#pragma unroll
    for (int ct = 0; ct < 4; ct++)
#pragma unroll
        for (int r = 0; r < 16; r++) {
            int c = ct * 32 + (r & 3) + 8 * (r >> 2) + 4 * h;
            yb[(size_t)c * N_ + qg] = (short)bf16rne(yacc[ct][r]);
        }
    if (h == 0) {
        float* mlb = ml + ((split * B_ + b) * 2) * N_;
        mlb[qg] = mI;
        mlb[N_ + qg] = lI;
    }
}

// ---------------- fused merge(4 splits) + Wy MFMA + bias -> d_out ----------------
// out[b][d][n] = Wb[d] + sum_c W[d][c] * y_merged[c][n].
// grid (N/32, B), block 256 = 4 waves; wave w owns d-tiles {2w,2w+1} x 32 n.
__global__ __launch_bounds__(256) void wy_merge_kernel(
    const short* __restrict__ yp, const float* __restrict__ ml,
    const short* __restrict__ wall2, const float* __restrict__ Wb,
    float* __restrict__ out)
{
    const int tid = threadIdx.x;
    const int wave = tid >> 6, lane = tid & 63;
    const int l = lane & 31, h = lane >> 5;
    const int b = blockIdx.y;
    const int n = blockIdx.x * 32 + l;

    // merge coefficients for this lane's n (m values are log2-domain)
    float m[4], lv[4];
#pragma unroll
    for (int sp = 0; sp < 4; sp++) {
        const float* mlb = ml + ((sp * B_ + b) * 2) * N_;
        m[sp] = mlb[n];
        lv[sp] = mlb[N_ + n];
    }
    float mmax = fmaxf(fmaxf(m[0], m[1]), fmaxf(m[2], m[3]));
    float e[4], den = 0.f;
#pragma unroll
    for (int sp = 0; sp < 4; sp++) { e[sp] = exp2fast(m[sp] - mmax); den += lv[sp] * e[sp]; }
    float inv = 1.0f / den;
#pragma unroll
    for (int sp = 0; sp < 4; sp++) e[sp] *= inv;

    // B-fragments: by[s][j] = y_merged[c = 16s + 8h + j][n]  (coalesced ushort loads)
    const unsigned short* ypu = (const unsigned short*)yp;
    bfrag by[8];
#pragma unroll
    for (int s = 0; s < 8; s++) {
#pragma unroll
        for (int j = 0; j < 8; j++) {
            const int c = s * 16 + h * 8 + j;
            float a = 0.f;
#pragma unroll
            for (int sp = 0; sp < 4; sp++) {
                unsigned short v = ypu[(((size_t)sp * B_ + b) * CI_ + c) * N_ + n];
                a = fmaf(e[sp], __uint_as_float((unsigned)v << 16), a);
            }
            by[s][j] = (short)bf16rne(a);
        }
    }

    f16v acc[2];
#pragma unroll
    for (int rt = 0; rt < 2; rt++)
#pragma unroll
        for (int r = 0; r < 16; r++) acc[rt][r] = 0.f;

#pragma unroll
    for (int s = 0; s < 8; s++)
#pragma unroll
        for (int rt = 0; rt < 2; rt++) {
            bfrag aw = *(const bfrag*)&wall2[((wave * 2 + rt) * 32 + l) * 128 + s * 16 + h * 8];
            acc[rt] = __builtin_amdgcn_mfma_f32_32x32x16_bf16(aw, by[s], acc[rt], 0, 0, 0);
        }

#pragma unroll
    for (int rt = 0; rt < 2; rt++)
#pragma unroll
        for (int r = 0; r < 16; r++) {
            const int d = (wave * 2 + rt) * 32 + (r & 3) + 8 * (r >> 2) + 4 * h;
            out[((size_t)b * D_ + d) * N_ + n] = acc[rt][r] + Wb[d];
        }
}

// ---------------- per-channel batch stats over (b, n) ----------------
__global__ __launch_bounds__(256) void stats_kernel(
    const float* __restrict__ wy, float* __restrict__ mean, float* __restrict__ rstd)
{
    __shared__ float ssum[256], ssq[256];
    int d = blockIdx.x;
    int tid = threadIdx.x;
    float s = 0.f, sq = 0.f;
    for (int b = 0; b < B_; b++) {
        const float* p = wy + (size_t)b * D_ * N_ + (size_t)d * N_;
        for (int i = tid; i < N_; i += 256) {
            float v = p[i];
            s += v;
            sq = fmaf(v, v, sq);
        }
    }
    ssum[tid] = s; ssq[tid] = sq;
    __syncthreads();
    for (int st = 128; st > 0; st >>= 1) {
        if (tid < st) { ssum[tid] += ssum[tid + st]; ssq[tid] += ssq[tid + st]; }
        __syncthreads();
    }
    if (tid == 0) {
        float inv = 1.0f / (float)(B_ * N_);
        float mn = ssum[0] * inv;
        float var = ssq[0] * inv - mn * mn;
        mean[d] = mn;
        rstd[d] = rsqrtf(var + BN_EPS_);
    }
}

// ---------------- BN (affine) + residual, in-place on d_out ----------------
__global__ __launch_bounds__(256) void bn_res_kernel(
    float* __restrict__ out, const float* __restrict__ f,
    const float* __restrict__ mean, const float* __restrict__ rstd,
    const float* __restrict__ gamma, const float* __restrict__ beta)
{
    int i = blockIdx.x * 256 + threadIdx.x;
    size_t e = (size_t)i * 4;
    int d = (int)((e >> 13) & 255);
    float4 wy = ((const float4*)out)[i];
    float4 ff = ((const float4*)f)[i];
    float sc = rstd[d] * gamma[d];
    float mn = mean[d];
    float bt = beta[d];
    float4 r;
    r.x = (wy.x - mn) * sc + bt + ff.x;
    r.y = (wy.y - mn) * sc + bt + ff.y;
    r.z = (wy.z - mn) * sc + bt + ff.z;
    r.w = (wy.w - mn) * sc + bt + ff.w;
    ((float4*)out)[i] = r;
}

extern "C" void kernel_launch(void* const* d_in, const int* in_sizes, int n_in,
                              void* d_out, int out_size, void* d_ws, size_t ws_size,
                              hipStream_t stream)
{
    const float* f   = (const float*)d_in[0];
    const float* g_w = (const float*)d_in[1];
    const float* g_b = (const float*)d_in[2];
    const float* t_w = (const float*)d_in[3];
    const float* t_b = (const float*)d_in[4];
    const float* p_w = (const float*)d_in[5];
    const float* p_b = (const float*)d_in[6];
    const float* W_w = (const float*)d_in[7];
    const float* W_b = (const float*)d_in[8];
    const float* gam = (const float*)d_in[9];
    const float* bet = (const float*)d_in[10];
    float* out = (float*)d_out;
    float* ws = (float*)d_ws;

    short* wall  = (short*)(ws + OFF_WALL);
    short* wall2 = wall + 3 * 32768;
    short* th_t = (short*)(ws + OFF_THT);
    short* ph_t = (short*)(ws + OFF_PHT);
    short* g_t  = (short*)(ws + OFF_GT);
    short* ypart = (short*)(ws + OFF_YP);
    float* mlp = ws + OFF_ML;
    float* mnp = ws + OFF_MEAN;
    float* rsp = ws + OFF_RSTD;

    wconv_kernel<<<512, 256, 0, stream>>>(g_w, t_w, p_w, W_w, wall);
    proj_kernel<<<dim3(N_ / 32, B_), 256, 0, stream>>>(f, wall, t_b, g_b, p_b,
                                                       th_t, g_t, ph_t);
    attn_kernel<<<512, 256, 0, stream>>>(th_t, ph_t, g_t, ypart, mlp);
    wy_merge_kernel<<<dim3(N_ / 32, B_), 256, 0, stream>>>(ypart, mlp, wall2, W_b, out);
    stats_kernel<<<D_, 256, 0, stream>>>(out, mnp, rsp);
    bn_res_kernel<<<(B_ * D_ * N_ / 4) / 256, 256, 0, stream>>>(out, f, mnp, rsp, gam, bet);
}

// Round 3
// 186.324 us; speedup vs baseline: 1.2494x; 1.2494x over previous
//
#include <hip/hip_runtime.h>
#include <hip/hip_bf16.h>
#include <math.h>

#define B_ 2
#define D_ 256
#define N_ 8192
#define CI_ 128
#define M_ 4096
#define BN_EPS_ 1e-5f
#define LOG2E_ 1.4426950408889634f

#define GLOBAL_AS __attribute__((address_space(1)))
#define LDS_AS __attribute__((address_space(3)))

// ---- workspace layout (float offsets) ----
#define OFF_WALL 0                          // bf16 wall[384][256] + wall2[256][128]
#define OFF_THT  65536                      // theta bf16 [B][N][CI]  (pre-scaled by log2 e)
#define OFF_PHT  (OFF_THT + 1048576)        // phi   bf16 [B][M][CI]
#define OFF_GT   (OFF_PHT + 524288)         // g     bf16 [B][CI][M]
#define OFF_YP   (OFF_GT  + 524288)         // y partial bf16 [4][B][CI][N]
#define OFF_ML   (OFF_YP  + 4194304)        // m/l fp32 [4][B][2][N]  (m in log2 domain)
#define OFF_MEAN (OFF_ML + 131072)
#define OFF_RSTD (OFF_MEAN + 256)

typedef __attribute__((ext_vector_type(8))) short bfrag;    // 8 bf16 = 4 VGPRs
typedef __attribute__((ext_vector_type(4))) float f4v;      // 16x16 accumulator
typedef __attribute__((ext_vector_type(16))) float f16v;    // 32x32 accumulator
typedef __attribute__((ext_vector_type(4))) short s4v;      // 4 bf16
typedef __attribute__((ext_vector_type(4))) unsigned u4v;   // 4 dwords (for reg-only pf build)

__device__ inline unsigned short bf16rne(float x) {
    unsigned u = __float_as_uint(x);
    u += 0x7fff + ((u >> 16) & 1);
    return (unsigned short)(u >> 16);
}

// 2^x via v_exp_f32 directly (no ocml denorm path, no log2e mul)
__device__ inline float exp2fast(float x) {
    float r;
    asm("v_exp_f32 %0, %1" : "=v"(r) : "v"(x));
    return r;
}

// ---------------- pack weights to bf16: wall[384][256] (g|theta|phi), wall2[256][128] (W) ----
// theta weights are pre-scaled by log2(e) so attention softmax runs in exp2 domain.
__global__ __launch_bounds__(256) void wconv_kernel(
    const float* __restrict__ gw, const float* __restrict__ tw, const float* __restrict__ pw,
    const float* __restrict__ Ww, short* __restrict__ wall)
{
    int idx = blockIdx.x * 256 + threadIdx.x;      // 0 .. 131071
    int which = idx >> 15;
    int rem = idx & 32767;
    const float* src = (which == 0) ? gw : (which == 1) ? tw : (which == 2) ? pw : Ww;
    float v = src[rem];
    if (which == 1) v *= LOG2E_;
    wall[idx] = (short)bf16rne(v);
}

// ---------------- MFMA projections ----------------
// Out[cc][n] = sum_d Wall[cc][d] * f[b][d][n], cc in [0,384): g | theta | phi.
// block 256 = 4 waves; wave owns 96 cc (6 frags) x 32 n (2 frags). grid (N/32, B).
__global__ __launch_bounds__(256, 2) void proj_kernel(
    const float* __restrict__ f, const short* __restrict__ wall,
    const float* __restrict__ tb, const float* __restrict__ gb, const float* __restrict__ pb,
    short* __restrict__ th_t, short* __restrict__ g_t, short* __restrict__ ph_t)
{
    __shared__ short sF[32 * 72];   // f chunk transposed [n][k], stride 72 shorts

    const int tid = threadIdx.x;
    const int wave = tid >> 6, lane = tid & 63;
    const int lq = lane & 15, quad = lane >> 4;
    const int b = blockIdx.y;
    const int n0 = blockIdx.x * 32;

    const float* fb = f + (size_t)b * D_ * N_;

    f4v acc[6][2];
#pragma unroll
    for (int ct = 0; ct < 6; ct++)
#pragma unroll
        for (int nf = 0; nf < 2; nf++) acc[ct][nf] = (f4v){0.f, 0.f, 0.f, 0.f};

    const int sn = tid & 31;     // staging: n within tile
    const int sgrp = tid >> 5;   // staging: d' group of 8

    for (int kc = 0; kc < D_; kc += 64) {
        __syncthreads();
#pragma unroll
        for (int jj = 0; jj < 4; jj++) {
            int dd = kc + sgrp * 8 + 2 * jj;
            float v0 = fb[(size_t)dd * N_ + n0 + sn];
            float v1 = fb[(size_t)(dd + 1) * N_ + n0 + sn];
            unsigned pk = (unsigned)bf16rne(v0) | ((unsigned)bf16rne(v1) << 16);
            *(unsigned*)&sF[sn * 72 + sgrp * 8 + 2 * jj] = pk;
        }
        __syncthreads();

        bfrag afr[6][2], bfr[2][2];
#pragma unroll
        for (int ks = 0; ks < 2; ks++) {
#pragma unroll
            for (int nf = 0; nf < 2; nf++)
                bfr[nf][ks] = *(const bfrag*)&sF[(nf * 16 + lq) * 72 + ks * 32 + quad * 8];
#pragma unroll
            for (int ct = 0; ct < 6; ct++)
                afr[ct][ks] = *(const bfrag*)&wall[(wave * 96 + ct * 16 + lq) * 256 + kc + ks * 32 + quad * 8];
        }
#pragma unroll
        for (int ks = 0; ks < 2; ks++)
#pragma unroll
            for (int ct = 0; ct < 6; ct++) {
                acc[ct][0] = __builtin_amdgcn_mfma_f32_16x16x32_bf16(afr[ct][ks], bfr[0][ks], acc[ct][0], 0, 0, 0);
                acc[ct][1] = __builtin_amdgcn_mfma_f32_16x16x32_bf16(afr[ct][ks], bfr[1][ks], acc[ct][1], 0, 0, 0);
            }
    }

#pragma unroll
    for (int ct = 0; ct < 6; ct++) {
        const int cf = wave * 6 + ct;
#pragma unroll
        for (int nf = 0; nf < 2; nf++) {
            f4v v = acc[ct][nf];
            const int n = n0 + nf * 16 + lq;
            if (cf < 8) {                 // g -> pooled, transposed [c][m]
                const int cb = cf * 16 + quad * 4;
                float pl[4];
#pragma unroll
                for (int r = 0; r < 4; r++) {
                    float o = __shfl_xor(v[r], 1);
                    pl[r] = fmaxf(v[r], o) + gb[cb + r];
                }
                if (!(lq & 1)) {
                    const int m = n >> 1;
#pragma unroll
                    for (int r = 0; r < 4; r++)
                        g_t[((size_t)b * CI_ + cb + r) * M_ + m] = (short)bf16rne(pl[r]);
                }
            } else if (cf < 16) {         // theta [n][c], log2e-scaled (weights already scaled)
                const int cb = (cf - 8) * 16 + quad * 4;
                s4v o;
#pragma unroll
                for (int r = 0; r < 4; r++) o[r] = (short)bf16rne(v[r] + tb[cb + r] * LOG2E_);
                *(s4v*)&th_t[((size_t)b * N_ + n) * CI_ + cb] = o;
            } else {                      // phi -> pooled [m][c]
                const int cb = (cf - 16) * 16 + quad * 4;
                float pl[4];
#pragma unroll
                for (int r = 0; r < 4; r++) {
                    float o = __shfl_xor(v[r], 1);
                    pl[r] = fmaxf(v[r], o) + pb[cb + r];
                }
                if (!(lq & 1)) {
                    const int m = n >> 1;
                    s4v o;
#pragma unroll
                    for (int r = 0; r < 4; r++) o[r] = (short)bf16rne(pl[r]);
                    *(s4v*)&ph_t[((size_t)b * M_ + m) * CI_ + cb] = o;
                }
            }
        }
    }
}

// ---------------- MFMA flash attention, 32x32 tiles, key-split 4 ----------------
// block 256 = 4 waves; wave owns 32 q. Q-tile 128, KC=64 keys/chunk, 16 chunks.
// R2 postmortem: 75 MB residual scratch (arch-VGPR class overflow: prefetch regs
// rph/rg lived across QK). R3: staging via global_load_lds DMA -> zero staging
// VGPRs, no vmcnt-drain-then-ds_write. XOR swizzles preserved by PRE-SWIZZLING
// the per-lane GLOBAL source address (LDS dest is linear base+lane*16):
//   sPh[64][128]: slot s of row r holds phi group s ^ (r&15)
//   sG [128][64]: slot u of row c holds g   group u ^ (c&7)   (linear 128B rows)
// One barrier per chunk; DMA for buf^1 issued right after the barrier has the
// whole chunk's compute to land before the next barrier's vmcnt drain.
__global__ __launch_bounds__(256, 2) void attn_kernel(
    const short* __restrict__ th_p, const short* __restrict__ ph_p,
    const short* __restrict__ g_p, short* __restrict__ yp, float* __restrict__ ml)
{
    __shared__ short sPh[2][64 * 128];  // phi [key][ci], 256B rows, XOR-16 swizzled slots
    __shared__ short sG [2][128 * 64];  // g^T [c][key], 128B rows, XOR-8 swizzled slots

    const int tid = threadIdx.x;
    const int wave = tid >> 6, lane = tid & 63;
    const int l = lane & 31, h = lane >> 5;

    // XCD-pinned decomposition: consecutive block ids round-robin across the 8
    // XCDs, and we have exactly 8 (b,split) pairs -> pin pair = bid&7.
    const int bid = blockIdx.x;
    const int b = bid & 1;
    const int split = (bid >> 1) & 3;
    const int q0 = (bid >> 3) * 128;
    const int qg = q0 + wave * 32 + l;

    // theta B-fragments in registers: B[k = 16s + 8h + j][n = q]
    const short* thr = th_p + ((size_t)b * N_ + qg) * CI_;
    bfrag tf[8];
#pragma unroll
    for (int s = 0; s < 8; s++)
        tf[s] = *(const bfrag*)&thr[s * 16 + h * 8];

    f16v yacc[4];
#pragma unroll
    for (int ct = 0; ct < 4; ct++)
#pragma unroll
        for (int r = 0; r < 16; r++) yacc[ct][r] = 0.f;
    float mI = -INFINITY, lI = 0.f;

    const short* phg = ph_p + (size_t)b * M_ * CI_;
    const short* gg  = g_p + (size_t)b * CI_ * M_;

    const int k0 = split * 1024;
    const int xm = l & 15;               // read-side swizzle mask for sPh

    // DMA staging: per wave, 4 issues phi (4 rows each) + 4 issues g (8 rows each).
    // HW writes LDS at uniform base + lane*16; global src carries the swizzle.
    const int prow = (lane >> 4);        // phi: row-within-4-group
    const int pslot = lane & 15;         // phi: 16B slot
    const int grow = (lane >> 3);        // g: row-within-8-group
    const int gslot = lane & 7;          // g: 16B slot
    const int gcg = gslot ^ grow;        // g global key-group (swizzle)

#define STAGE_DMA(BUF, KC)                                                                  \
    do {                                                                                    \
        _Pragma("unroll")                                                                   \
        for (int p = 0; p < 4; p++) {                                                       \
            const int rp = wave * 16 + p * 4 + prow;          /* row in [0,64) */           \
            const int cg = pslot ^ (p * 4 + prow);            /* swizzled ci-group */       \
            __builtin_amdgcn_global_load_lds(                                               \
                (const GLOBAL_AS void*)(phg + (size_t)((KC) + rp) * 128 + cg * 8),          \
                (LDS_AS void*)(&sPh[BUF][(wave * 16 + p * 4) * 128]), 16, 0, 0);            \
        }                                                                                   \
        _Pragma("unroll")                                                                   \
        for (int p = 0; p < 4; p++) {                                                       \
            const int cp = wave * 32 + p * 8 + grow;          /* c in [0,128) */            \
            __builtin_amdgcn_global_load_lds(                                               \
                (const GLOBAL_AS void*)(gg + (size_t)cp * M_ + (KC) + gcg * 8),             \
                (LDS_AS void*)(&sG[BUF][(wave * 32 + p * 8) * 64]), 16, 0, 0);              \
        }                                                                                   \
    } while (0)

    STAGE_DMA(0, k0);

    int cur = 0;
    for (int kc = k0; kc < k0 + 1024; kc += 64) {
        __syncthreads();                 // drains DMA vmcnt; buf[cur] complete for all waves
        const bool nxt = (kc + 64 < k0 + 1024);
        if (nxt) {
            STAGE_DMA(cur ^ 1, kc + 64); // in-flight across this chunk's compute
            __builtin_amdgcn_sched_barrier(0);   // pin DMA issue before the MFMA region
        }

        // S^T = phi . theta : 2 key-tiles of 32; lane holds col q = l, 16 key-rows/tile
        f16v sv[2];
        __builtin_amdgcn_s_setprio(1);
#pragma unroll
        for (int kt = 0; kt < 2; kt++) {
            f16v a;
#pragma unroll
            for (int r = 0; r < 16; r++) a[r] = 0.f;
#pragma unroll
            for (int s = 0; s < 8; s++) {
                bfrag pa = *(const bfrag*)&sPh[cur][(kt * 32 + l) * 128 + (((s << 1) | h) ^ xm) * 8];
                a = __builtin_amdgcn_mfma_f32_32x32x16_bf16(pa, tf[s], a, 0, 0, 0);
            }
            sv[kt] = a;
        }
        __builtin_amdgcn_s_setprio(0);

        // online softmax for q = l, exp2 domain (keys split across h halves: one shfl)
        float mx = fmaxf(sv[0][0], sv[1][0]);
#pragma unroll
        for (int r = 1; r < 16; r++) mx = fmaxf(mx, fmaxf(sv[0][r], sv[1][r]));
        mx = fmaxf(mx, __shfl_xor(mx, 32));

        // defer-max: only rescale when the running max grew by > 8 (p bounded by 2^8)
        if (__any(mx > mI + 8.f)) {
            float mnew = fmaxf(mI, mx);
            float al = exp2fast(mI - mnew);
            lI *= al;
#pragma unroll
            for (int ct = 0; ct < 4; ct++)
#pragma unroll
                for (int r = 0; r < 16; r++) yacc[ct][r] *= al;
            mI = mnew;
        }

        float ps = 0.f;
        // pack exp2(S) pairs: pw[kt*8 + b2*2 + p] holds keys kt*32 + 8*b2 + 4h + 2p + {0,1}
        unsigned pw[16];
#pragma unroll
        for (int kt = 0; kt < 2; kt++)
#pragma unroll
            for (int i = 0; i < 8; i++) {
                const int r = 2 * i;
                float p0 = exp2fast(sv[kt][r] - mI);
                float p1 = exp2fast(sv[kt][r + 1] - mI);
                ps += p0 + p1;
                unsigned pk;
                asm("v_cvt_pk_bf16_f32 %0, %1, %2" : "=v"(pk) : "v"(p0), "v"(p1));
                pw[kt * 8 + (i >> 1) * 2 + (i & 1)] = pk;
            }
        ps += __shfl_xor(ps, 32);
        lI += ps;

        // P -> B-operand frags: pf[s][j] = P[key = 16s + 8h + j][q = l].
        // value with key k: held at half bit2(k), needed at half bit3(k) -> one shfl_xor(32).
        // All pw[] indices are compile-time constants; h only selects VALUES (cndmask).
        // Register-only build: ext_vector element writes + bit_cast (NO union/address).
        bfrag pf[4];
#pragma unroll
        for (int s = 0; s < 4; s++) {
            const int kt = s >> 1;
            const int iA = kt * 8 + ((2 * s) & 3) * 2;       // block used when h==0 as "own"
            const int iB = kt * 8 + ((2 * s + 1) & 3) * 2;   // block used when h==1 as "own"
            unsigned A0 = pw[iA], A1 = pw[iA + 1];
            unsigned B0 = pw[iB], B1 = pw[iB + 1];
            unsigned O0 = h ? B0 : A0;
            unsigned O1 = h ? B1 : A1;
            unsigned Xs0 = h ? A0 : B0;
            unsigned Xs1 = h ? A1 : B1;
            unsigned X0 = (unsigned)__shfl_xor((int)Xs0, 32);
            unsigned X1 = (unsigned)__shfl_xor((int)Xs1, 32);
            u4v t;
            t.x = h ? X0 : O0;
            t.y = h ? X1 : O1;
            t.z = h ? O0 : X0;
            t.w = h ? O1 : X1;
            pf[s] = __builtin_bit_cast(bfrag, t);
        }

        // PV: y^T += g^T . P  (sG read swizzle: slot (2s+h) ^ (l&7))
        __builtin_amdgcn_s_setprio(1);
#pragma unroll
        for (int ct = 0; ct < 4; ct++)
#pragma unroll
            for (int s = 0; s < 4; s++) {
                bfrag ga = *(const bfrag*)&sG[cur][(ct * 32 + l) * 64 + ((((s << 1) | h) ^ (l & 7)) * 8)];
                yacc[ct] = __builtin_amdgcn_mfma_f32_32x32x16_bf16(ga, pf[s], yacc[ct], 0, 0, 0);
            }
        __builtin_amdgcn_s_setprio(0);

        cur ^= 1;
    }
#undef STAGE_DMA

    // epilogue: bf16 unnormalized partials + (m,l)  (m in log2 domain)
    short* yb = yp + (((size_t)split * B_ + b) * CI_) * N_;
#pragma unroll
    for (int ct = 0; ct < 4; ct++)
#pragma unroll
        for (int r = 0; r < 16; r++) {
            int c = ct * 32 + (r & 3) + 8 * (r >> 2) + 4 * h;
            yb[(size_t)c * N_ + qg] = (short)bf16rne(yacc[ct][r]);
        }
    if (h == 0) {
        float* mlb = ml + ((split * B_ + b) * 2) * N_;
        mlb[qg] = mI;
        mlb[N_ + qg] = lI;
    }
}

// ---------------- fused merge(4 splits) + Wy MFMA + bias -> d_out ----------------
// out[b][d][n] = Wb[d] + sum_c W[d][c] * y_merged[c][n].
// grid (N/32, B), block 256 = 4 waves; wave w owns d-tiles {2w,2w+1} x 32 n.
__global__ __launch_bounds__(256) void wy_merge_kernel(
    const short* __restrict__ yp, const float* __restrict__ ml,
    const short* __restrict__ wall2, const float* __restrict__ Wb,
    float* __restrict__ out)
{
    const int tid = threadIdx.x;
    const int wave = tid >> 6, lane = tid & 63;
    const int l = lane & 31, h = lane >> 5;
    const int b = blockIdx.y;
    const int n = blockIdx.x * 32 + l;

    // merge coefficients for this lane's n (m values are log2-domain)
    float m[4], lv[4];
#pragma unroll
    for (int sp = 0; sp < 4; sp++) {
        const float* mlb = ml + ((sp * B_ + b) * 2) * N_;
        m[sp] = mlb[n];
        lv[sp] = mlb[N_ + n];
    }
    float mmax = fmaxf(fmaxf(m[0], m[1]), fmaxf(m[2], m[3]));
    float e[4], den = 0.f;
#pragma unroll
    for (int sp = 0; sp < 4; sp++) { e[sp] = exp2fast(m[sp] - mmax); den += lv[sp] * e[sp]; }
    float inv = 1.0f / den;
#pragma unroll
    for (int sp = 0; sp < 4; sp++) e[sp] *= inv;

    // B-fragments: by[s][j] = y_merged[c = 16s + 8h + j][n]  (coalesced ushort loads)
    const unsigned short* ypu = (const unsigned short*)yp;
    bfrag by[8];
#pragma unroll
    for (int s = 0; s < 8; s++) {
#pragma unroll
        for (int j = 0; j < 8; j++) {
            const int c = s * 16 + h * 8 + j;
            float a = 0.f;
#pragma unroll
            for (int sp = 0; sp < 4; sp++) {
                unsigned short v = ypu[(((size_t)sp * B_ + b) * CI_ + c) * N_ + n];
                a = fmaf(e[sp], __uint_as_float((unsigned)v << 16), a);
            }
            by[s][j] = (short)bf16rne(a);
        }
    }

    f16v acc[2];
#pragma unroll
    for (int rt = 0; rt < 2; rt++)
#pragma unroll
        for (int r = 0; r < 16; r++) acc[rt][r] = 0.f;

#pragma unroll
    for (int s = 0; s < 8; s++)
#pragma unroll
        for (int rt = 0; rt < 2; rt++) {
            bfrag aw = *(const bfrag*)&wall2[((wave * 2 + rt) * 32 + l) * 128 + s * 16 + h * 8];
            acc[rt] = __builtin_amdgcn_mfma_f32_32x32x16_bf16(aw, by[s], acc[rt], 0, 0, 0);
        }

#pragma unroll
    for (int rt = 0; rt < 2; rt++)
#pragma unroll
        for (int r = 0; r < 16; r++) {
            const int d = (wave * 2 + rt) * 32 + (r & 3) + 8 * (r >> 2) + 4 * h;
            out[((size_t)b * D_ + d) * N_ + n] = acc[rt][r] + Wb[d];
        }
}

// ---------------- per-channel batch stats over (b, n) ----------------
__global__ __launch_bounds__(256) void stats_kernel(
    const float* __restrict__ wy, float* __restrict__ mean, float* __restrict__ rstd)
{
    __shared__ float ssum[256], ssq[256];
    int d = blockIdx.x;
    int tid = threadIdx.x;
    float s = 0.f, sq = 0.f;
    for (int b = 0; b < B_; b++) {
        const float* p = wy + (size_t)b * D_ * N_ + (size_t)d * N_;
        for (int i = tid; i < N_; i += 256) {
            float v = p[i];
            s += v;
            sq = fmaf(v, v, sq);
        }
    }
    ssum[tid] = s; ssq[tid] = sq;
    __syncthreads();
    for (int st = 128; st > 0; st >>= 1) {
        if (tid < st) { ssum[tid] += ssum[tid + st]; ssq[tid] += ssq[tid + st]; }
        __syncthreads();
    }
    if (tid == 0) {
        float inv = 1.0f / (float)(B_ * N_);
        float mn = ssum[0] * inv;
        float var = ssq[0] * inv - mn * mn;
        mean[d] = mn;
        rstd[d] = rsqrtf(var + BN_EPS_);
    }
}

// ---------------- BN (affine) + residual, in-place on d_out ----------------
__global__ __launch_bounds__(256) void bn_res_kernel(
    float* __restrict__ out, const float* __restrict__ f,
    const float* __restrict__ mean, const float* __restrict__ rstd,
    const float* __restrict__ gamma, const float* __restrict__ beta)
{
    int i = blockIdx.x * 256 + threadIdx.x;
    size_t e = (size_t)i * 4;
    int d = (int)((e >> 13) & 255);
    float4 wy = ((const float4*)out)[i];
    float4 ff = ((const float4*)f)[i];
    float sc = rstd[d] * gamma[d];
    float mn = mean[d];
    float bt = beta[d];
    float4 r;
    r.x = (wy.x - mn) * sc + bt + ff.x;
    r.y = (wy.y - mn) * sc + bt + ff.y;
    r.z = (wy.z - mn) * sc + bt + ff.z;
    r.w = (wy.w - mn) * sc + bt + ff.w;
    ((float4*)out)[i] = r;
}

extern "C" void kernel_launch(void* const* d_in, const int* in_sizes, int n_in,
                              void* d_out, int out_size, void* d_ws, size_t ws_size,
                              hipStream_t stream)
{
    const float* f   = (const float*)d_in[0];
    const float* g_w = (const float*)d_in[1];
    const float* g_b = (const float*)d_in[2];
    const float* t_w = (const float*)d_in[3];
    const float* t_b = (const float*)d_in[4];
    const float* p_w = (const float*)d_in[5];
    const float* p_b = (const float*)d_in[6];
    const float* W_w = (const float*)d_in[7];
    const float* W_b = (const float*)d_in[8];
    const float* gam = (const float*)d_in[9];
    const float* bet = (const float*)d_in[10];
    float* out = (float*)d_out;
    float* ws = (float*)d_ws;

    short* wall  = (short*)(ws + OFF_WALL);
    short* wall2 = wall + 3 * 32768;
    short* th_t = (short*)(ws + OFF_THT);
    short* ph_t = (short*)(ws + OFF_PHT);
    short* g_t  = (short*)(ws + OFF_GT);
    short* ypart = (short*)(ws + OFF_YP);
    float* mlp = ws + OFF_ML;
    float* mnp = ws + OFF_MEAN;
    float* rsp = ws + OFF_RSTD;

    wconv_kernel<<<512, 256, 0, stream>>>(g_w, t_w, p_w, W_w, wall);
    proj_kernel<<<dim3(N_ / 32, B_), 256, 0, stream>>>(f, wall, t_b, g_b, p_b,
                                                       th_t, g_t, ph_t);
    attn_kernel<<<512, 256, 0, stream>>>(th_t, ph_t, g_t, ypart, mlp);
    wy_merge_kernel<<<dim3(N_ / 32, B_), 256, 0, stream>>>(ypart, mlp, wall2, W_b, out);
    stats_kernel<<<D_, 256, 0, stream>>>(out, mnp, rsp);
    bn_res_kernel<<<(B_ * D_ * N_ / 4) / 256, 256, 0, stream>>>(out, f, mnp, rsp, gam, bet);
}